// Round 8
// baseline (248.072 us; speedup 1.0000x reference)
//
#include <hip/hip_runtime.h>
#include <hip/hip_bf16.h>

#define BATCH 8
#define NC 2048
#define NF 8192
#define CDIM 256
#define CSKIP 64
#define OUTD 256
#define MTOT (BATCH*NF)   // 65536
#define NCTOT (BATCH*NC)  // 16384
#define NCHUNK 8          // kNN coarse-scan split
#define CHSZ (NC/NCHUNK)  // 256

typedef __attribute__((ext_vector_type(8))) short short8;
typedef __attribute__((ext_vector_type(4))) float floatx4;

static __device__ __forceinline__ ushort f2bf(float f) {
    union { float f; unsigned u; } v; v.f = f;
    unsigned r = v.u + 0x7fffu + ((v.u >> 16) & 1u);   // RNE
    return (ushort)(r >> 16);
}
static __device__ __forceinline__ float bf2f(ushort u) {
    union { unsigned u; float f; } v; v.u = ((unsigned)u) << 16;
    return v.f;
}

#if defined(__has_builtin) && __has_builtin(__builtin_amdgcn_fmed3f)
#define MED3F(a, b, c) __builtin_amdgcn_fmed3f((a), (b), (c))
#else
static __device__ __forceinline__ float MED3F(float a, float b, float c) {
    return fmaxf(fminf(a, b), fminf(fmaxf(a, b), c));
}
#endif

// branchless strict-< top-3 insert (exact jax top_k tie order when fed ascending j)
#define TOP3_INS(d, jj, D0, D1, D2, I0, I1, I2)     \
    {                                               \
        bool c2 = (d) < D2, c1 = (d) < D1, c0 = (d) < D0; \
        I2 = c1 ? I1 : (c2 ? (jj) : I2);            \
        I1 = c0 ? I0 : (c1 ? (jj) : I1);            \
        I0 = c0 ? (jj) : I0;                        \
        D2 = MED3F(D1, D2, (d));                    \
        D1 = MED3F(D0, D1, (d));                    \
        D0 = fminf(D0, (d));                        \
    }

// ---- kernel 1: prep (bf16 casts, pos padding, tail outputs, weight transposes).
// All segments are multiples of 256 so the LDS-tiled transpose segment starts
// on a block boundary (it needs whole blocks for __shared__ + barrier).
#define SEG0 1048576   // x -> xb bf16 (float4-wide)
#define SEG1 1048576   // x_skip -> xsb bf16
#define SEG5 16384     // pos -> pos4
#define SEG6 (MTOT*3)  // pos_skip -> out tail
#define SEG7 MTOT      // batch ids -> out tail
#define SEGW (36*256)  // weight transpose (36 pseudo-blocks)
#define PREP_THREADS (SEG0+SEG1+SEG5+SEG6+SEG7+SEGW)

__global__ __launch_bounds__(256) void prep_kernel(const float* __restrict__ x,
                                                   const float* __restrict__ x_skip,
                                                   const float* __restrict__ pos,
                                                   const float* __restrict__ pos_skip,
                                                   const float* __restrict__ W1,
                                                   const float* __restrict__ W2,
                                                   ushort* __restrict__ xb,
                                                   ushort* __restrict__ xsb,
                                                   float4* __restrict__ pos4,
                                                   ushort* __restrict__ Bt1a,
                                                   ushort* __restrict__ Bt1b,
                                                   ushort* __restrict__ Bt2,
                                                   float* __restrict__ out) {
    __shared__ ushort tile[64 * 65];
    int t = blockIdx.x * 256 + threadIdx.x;
    if (t < SEG0) {
        float4 v = ((const float4*)x)[t];
        ushort4 p; p.x = f2bf(v.x); p.y = f2bf(v.y); p.z = f2bf(v.z); p.w = f2bf(v.w);
        ((ushort4*)xb)[t] = p;
        return;
    }
    t -= SEG0;
    if (t < SEG1) {
        float4 v = ((const float4*)x_skip)[t];
        ushort4 p; p.x = f2bf(v.x); p.y = f2bf(v.y); p.z = f2bf(v.z); p.w = f2bf(v.w);
        ((ushort4*)xsb)[t] = p;
        return;
    }
    t -= SEG1;
    if (t < SEG5) {
        float4 q;
        q.x = pos[t * 3 + 0]; q.y = pos[t * 3 + 1]; q.z = pos[t * 3 + 2]; q.w = 0.f;
        pos4[t] = q;
        return;
    }
    t -= SEG5;
    if (t < SEG6) {
        out[(size_t)MTOT * OUTD + t] = pos_skip[t];
        return;
    }
    t -= SEG6;
    if (t < SEG7) {
        out[(size_t)MTOT * OUTD + (size_t)MTOT * 3 + t] = (float)(t >> 13);
        return;
    }
    t -= SEG7;
    if (t < SEGW) {
        // 64x64 LDS-tiled weight transpose; pad 65 breaks bank conflicts.
        int bid = t >> 8;
        int tx = t & 63, ty = (t >> 6) & 3;
        const float* src; ushort* dst; int k0, n0, KD;
        if (bid < 16)      { src = W1;             dst = Bt1a; k0 = (bid >> 2) * 64; n0 = (bid & 3) * 64; KD = 256; }
        else if (bid < 20) { src = W1 + 256 * 256; dst = Bt1b; k0 = 0;               n0 = (bid - 16) * 64; KD = 64; }
        else               { int b2 = bid - 20; src = W2; dst = Bt2; k0 = (b2 >> 2) * 64; n0 = (b2 & 3) * 64; KD = 256; }
#pragma unroll
        for (int r = 0; r < 64; r += 4) {
            int k = r + ty;
            tile[k * 65 + tx] = f2bf(src[(size_t)(k0 + k) * 256 + n0 + tx]);
        }
        __syncthreads();
#pragma unroll
        for (int r = 0; r < 64; r += 4) {
            int n = r + ty;
            dst[(size_t)(n0 + n) * KD + k0 + tx] = tile[tx * 65 + n];
        }
    }
}

// ---- kernel 2: chunked kNN partials, 4 fine points per thread.
// 4 independent insert chains/thread cover the dependent med3/cndmask latency;
// LDS reads + jj arithmetic amortized 4x. SoA chunk in LDS (round-3 lesson:
// never wave-uniform global loads -> s_load serialization).
__global__ __launch_bounds__(256) void knn_part(const float4* __restrict__ pos4,
                                                const float* __restrict__ pos_skip,
                                                int* __restrict__ pidx,
                                                float* __restrict__ pdst) {
    __shared__ float sx[CHSZ], sy[CHSZ], sz[CHSZ];     // 3 KB
    int c = blockIdx.x & (NCHUNK - 1);
    int m0 = (blockIdx.x >> 3) * 1024 + threadIdx.x;   // +0,+256,+512,+768
    int b = m0 >> 13;                                  // all 4 in same cloud
    int jbase = b * NC + c * CHSZ;

    float4 q0 = pos4[jbase + threadIdx.x];
    sx[threadIdx.x] = q0.x; sy[threadIdx.x] = q0.y; sz[threadIdx.x] = q0.z;

    float px[4], py[4], pz[4];
#pragma unroll
    for (int p = 0; p < 4; ++p) {
        int m = m0 + p * 256;
        px[p] = pos_skip[m * 3 + 0];
        py[p] = pos_skip[m * 3 + 1];
        pz[p] = pos_skip[m * 3 + 2];
    }
    __syncthreads();

    float d0[4], d1[4], d2[4];
    int i0[4], i1[4], i2[4];
#pragma unroll
    for (int p = 0; p < 4; ++p) {
        d0[p] = 1e30f; d1[p] = 1e30f; d2[p] = 1e30f;
        i0[p] = jbase; i1[p] = jbase; i2[p] = jbase;
    }

#pragma unroll 2
    for (int j4 = 0; j4 < CHSZ; j4 += 4) {
        float4 qx = *(const float4*)&sx[j4];
        float4 qy = *(const float4*)&sy[j4];
        float4 qz = *(const float4*)&sz[j4];
#pragma unroll
        for (int u = 0; u < 4; ++u) {
            int jj = jbase + j4 + u;
#pragma unroll
            for (int p = 0; p < 4; ++p) {
                float ax = px[p] - qx[u], ay = py[p] - qy[u], az = pz[p] - qz[u];
                float d = ax * ax + ay * ay + az * az;
                TOP3_INS(d, jj, d0[p], d1[p], d2[p], i0[p], i1[p], i2[p]);
            }
        }
    }
#pragma unroll
    for (int p = 0; p < 4; ++p) {
        int m = m0 + p * 256;
        size_t base = ((size_t)c * MTOT + m) * 3;
        pdst[base + 0] = d0[p]; pdst[base + 1] = d1[p]; pdst[base + 2] = d2[p];
        pidx[base + 0] = i0[p]; pidx[base + 1] = i1[p]; pidx[base + 2] = i2[p];
    }
}

// ---- kernel 3: merged mid-kernel. Blocks 0..255: Gb = bf16(xb @ Bt1a^T)
// (B staged in block-shared LDS k-slices — round-6 lesson). Blocks 256..511:
// knn_merge (independent work, overlaps the GEMM; one launch gap saved).
#define GW_STRIDE 72
__global__ __launch_bounds__(256) void mid_kernel(const ushort* __restrict__ A,
                                                  const ushort* __restrict__ Bt,
                                                  ushort* __restrict__ Gb,
                                                  const int* __restrict__ pidx,
                                                  const float* __restrict__ pdst,
                                                  int* __restrict__ idxw,
                                                  float* __restrict__ wgt) {
    __shared__ ushort wB[256 * GW_STRIDE];             // 36 KB
    int tid = threadIdx.x;
    if (blockIdx.x >= NCTOT / 64) {
        // ---- knn_merge part
        int m = (blockIdx.x - NCTOT / 64) * 256 + tid;
        float d0 = 1e30f, d1 = 1e30f, d2 = 1e30f;
        int i0 = 0, i1 = 0, i2 = 0;
#pragma unroll
        for (int c = 0; c < NCHUNK; ++c) {
            size_t base = ((size_t)c * MTOT + m) * 3;
#pragma unroll
            for (int s = 0; s < 3; ++s) {
                float d = pdst[base + s];
                int jj = pidx[base + s];
                TOP3_INS(d, jj, d0, d1, d2, i0, i1, i2);
            }
        }
        float w0 = 1.0f / fmaxf(d0, 1e-16f);
        float w1 = 1.0f / fmaxf(d1, 1e-16f);
        float w2 = 1.0f / fmaxf(d2, 1e-16f);
        float inv = 1.0f / (w0 + w1 + w2);
        idxw[m * 3 + 0] = i0;  wgt[m * 3 + 0] = w0 * inv;
        idxw[m * 3 + 1] = i1;  wgt[m * 3 + 1] = w1 * inv;
        idxw[m * 3 + 2] = i2;  wgt[m * 3 + 2] = w2 * inv;
        return;
    }
    // ---- gemm_G part
    int wave = tid >> 6, lane = tid & 63;
    int m0 = blockIdx.x * 64 + wave * 16;
    int lrow = lane & 15;
    int ko = (lane >> 4) * 8;

    floatx4 acc[16];
#pragma unroll
    for (int i = 0; i < 16; ++i) acc[i] = (floatx4){0.f, 0.f, 0.f, 0.f};

    for (int s = 0; s < 4; ++s) {
        if (s) __syncthreads();
        for (int cch = tid; cch < 2048; cch += 256) {
            int n = cch >> 3, koff = (cch & 7) * 8;
            *(short8*)&wB[n * GW_STRIDE + koff] = *(const short8*)(Bt + n * 256 + s * 64 + koff);
        }
        __syncthreads();
        const ushort* ar = A + (size_t)(m0 + lrow) * 256 + s * 64 + ko;
#pragma unroll
        for (int k0 = 0; k0 < 64; k0 += 32) {
            short8 af = *(const short8*)(ar + k0);
#pragma unroll
            for (int nt = 0; nt < 16; ++nt) {
                short8 bf = *(const short8*)&wB[(nt * 16 + lrow) * GW_STRIDE + k0 + ko];
                acc[nt] = __builtin_amdgcn_mfma_f32_16x16x32_bf16(af, bf, acc[nt], 0, 0, 0);
            }
        }
    }
    int rbase = (lane >> 4) * 4;
#pragma unroll
    for (int nt = 0; nt < 16; ++nt) {
        int n = nt * 16 + lrow;
#pragma unroll
        for (int r = 0; r < 4; ++r)
            Gb[(size_t)(m0 + rbase + r) * 256 + n] = f2bf(acc[nt][r]);
    }
}

// ---- kernel 4: fused  h1 = relu(x_skip@W1b + interp(Gb) + b1);  out = relu(h1@W2 + b2)
// (round-6 structure: block-shared LDS B, idx/wgt via vector path, pipelined gathers)
#define LDS_STRIDE 264
#define WB_STRIDE 72
__global__ __launch_bounds__(256) void fused_kernel(const ushort* __restrict__ xsb,
                                                    const ushort* __restrict__ Bt1b,
                                                    const ushort* __restrict__ Gb,
                                                    const int* __restrict__ idxw,
                                                    const float* __restrict__ wgt,
                                                    const float* __restrict__ b1,
                                                    const ushort* __restrict__ Bt2,
                                                    const float* __restrict__ b2,
                                                    float* __restrict__ out) {
    __shared__ ushort h1t[4][16 * LDS_STRIDE];     // 33792 B
    __shared__ ushort wB[256 * WB_STRIDE];         // 36864 B
    __shared__ int   sIdx[4][48];
    __shared__ float sWgt[4][48];                  // total ~72 KB -> 2 blk/CU
    int tid = threadIdx.x;
    int wave = tid >> 6, lane = tid & 63;
    int m0 = blockIdx.x * 64 + wave * 16;
    int lrow = lane & 15;
    int ko = (lane >> 4) * 8;
    int rbase = (lane >> 4) * 4;

    if (lane < 48) {
        sIdx[wave][lane] = idxw[m0 * 3 + lane];
        sWgt[wave][lane] = wgt[m0 * 3 + lane];
    }

    const ushort4* Gv = (const ushort4*)Gb;
    const int*   si = sIdx[wave];
    const float* sw = sWgt[wave];
    ushort4 g[4][3];
#define GATHER(slot, i) {                                         \
        int a0 = si[(i) * 3 + 0];                                 \
        int a1 = si[(i) * 3 + 1];                                 \
        int a2 = si[(i) * 3 + 2];                                 \
        g[slot][0] = Gv[(size_t)a0 * 64 + lane];                  \
        g[slot][1] = Gv[(size_t)a1 * 64 + lane];                  \
        g[slot][2] = Gv[(size_t)a2 * 64 + lane]; }

    GATHER(0, 0) GATHER(1, 1) GATHER(2, 2) GATHER(3, 3)

    for (int cch = tid; cch < 2048; cch += 256) {
        int n = cch >> 3, koff = (cch & 7) * 8;
        *(short8*)&wB[n * WB_STRIDE + koff] = *(const short8*)(Bt1b + n * 64 + koff);
    }
    __syncthreads();

    floatx4 acc[16];
#pragma unroll
    for (int i = 0; i < 16; ++i) acc[i] = (floatx4){0.f, 0.f, 0.f, 0.f};
    {
        const ushort* arow = xsb + (size_t)(m0 + lrow) * 64 + ko;
#pragma unroll
        for (int k0 = 0; k0 < 64; k0 += 32) {
            short8 af = *(const short8*)(arow + k0);
#pragma unroll
            for (int nt = 0; nt < 16; ++nt) {
                short8 bf = *(const short8*)&wB[(nt * 16 + lrow) * WB_STRIDE + k0 + ko];
                acc[nt] = __builtin_amdgcn_mfma_f32_16x16x32_bf16(af, bf, acc[nt], 0, 0, 0);
            }
        }
    }

    ushort* ht = h1t[wave];
#pragma unroll
    for (int nt = 0; nt < 16; ++nt) {
        int n = nt * 16 + lrow;
#pragma unroll
        for (int r = 0; r < 4; ++r)
            ht[(rbase + r) * LDS_STRIDE + n] = f2bf(acc[nt][r]);
    }

    {
        float4 bv = ((const float4*)b1)[lane];
#define COMBINE(i) {                                              \
        int s = (i) & 3;                                          \
        float w0 = sw[(i) * 3 + 0], w1 = sw[(i) * 3 + 1], w2 = sw[(i) * 3 + 2]; \
        ushort4 sv = *(const ushort4*)(ht + (i) * LDS_STRIDE + 4 * lane); \
        float4 h;                                                 \
        h.x = fmaxf(bf2f(sv.x) + w0 * bf2f(g[s][0].x) + w1 * bf2f(g[s][1].x) + w2 * bf2f(g[s][2].x) + bv.x, 0.f); \
        h.y = fmaxf(bf2f(sv.y) + w0 * bf2f(g[s][0].y) + w1 * bf2f(g[s][1].y) + w2 * bf2f(g[s][2].y) + bv.y, 0.f); \
        h.z = fmaxf(bf2f(sv.z) + w0 * bf2f(g[s][0].z) + w1 * bf2f(g[s][1].z) + w2 * bf2f(g[s][2].z) + bv.z, 0.f); \
        h.w = fmaxf(bf2f(sv.w) + w0 * bf2f(g[s][0].w) + w1 * bf2f(g[s][1].w) + w2 * bf2f(g[s][2].w) + bv.w, 0.f); \
        ushort4 hp;                                               \
        hp.x = f2bf(h.x); hp.y = f2bf(h.y); hp.z = f2bf(h.z); hp.w = f2bf(h.w); \
        *(ushort4*)(ht + (i) * LDS_STRIDE + 4 * lane) = hp; }

#pragma unroll
        for (int i = 0; i < 12; ++i) { COMBINE(i); GATHER(i & 3, i + 4); }
#pragma unroll
        for (int i = 12; i < 16; ++i) { COMBINE(i); }
#undef GATHER
#undef COMBINE
    }

#pragma unroll
    for (int i = 0; i < 16; ++i) acc[i] = (floatx4){0.f, 0.f, 0.f, 0.f};
    for (int s = 0; s < 4; ++s) {
        __syncthreads();
        for (int cch = tid; cch < 2048; cch += 256) {
            int n = cch >> 3, koff = (cch & 7) * 8;
            *(short8*)&wB[n * WB_STRIDE + koff] = *(const short8*)(Bt2 + n * 256 + s * 64 + koff);
        }
        __syncthreads();
        const ushort* ar = ht + lrow * LDS_STRIDE + s * 64 + ko;
#pragma unroll
        for (int k0 = 0; k0 < 64; k0 += 32) {
            short8 af = *(const short8*)(ar + k0);
#pragma unroll
            for (int nt = 0; nt < 16; ++nt) {
                short8 bf = *(const short8*)&wB[(nt * 16 + lrow) * WB_STRIDE + k0 + ko];
                acc[nt] = __builtin_amdgcn_mfma_f32_16x16x32_bf16(af, bf, acc[nt], 0, 0, 0);
            }
        }
    }
#pragma unroll
    for (int nt = 0; nt < 16; ++nt) {
        int n = nt * 16 + lrow;
        float bv2 = b2[n];
#pragma unroll
        for (int r = 0; r < 4; ++r) {
            float v = fmaxf(acc[nt][r] + bv2, 0.f);
            out[(size_t)(m0 + rbase + r) * OUTD + n] = v;
        }
    }
}

extern "C" void kernel_launch(void* const* d_in, const int* in_sizes, int n_in,
                              void* d_out, int out_size, void* d_ws, size_t ws_size,
                              hipStream_t stream) {
    const float* x        = (const float*)d_in[0];
    const float* pos      = (const float*)d_in[1];
    const float* x_skip   = (const float*)d_in[3];
    const float* pos_skip = (const float*)d_in[4];
    const float* W1       = (const float*)d_in[6];
    const float* b1       = (const float*)d_in[7];
    const float* W2       = (const float*)d_in[8];
    const float* b2       = (const float*)d_in[9];

    char* ws = (char*)d_ws;
    size_t off = 0;
    int*    idxw = (int*)(ws + off);    off += (size_t)MTOT * 3 * 4;      //  768 KB
    float*  wgt  = (float*)(ws + off);  off += (size_t)MTOT * 3 * 4;      //  768 KB
    ushort* xb   = (ushort*)(ws + off); off += (size_t)NCTOT * 256 * 2;   //    8 MB
    ushort* xsb  = (ushort*)(ws + off); off += (size_t)MTOT * 64 * 2;     //    8 MB
    ushort* Gb   = (ushort*)(ws + off); off += (size_t)NCTOT * 256 * 2;   //    8 MB
    ushort* Bt1a = (ushort*)(ws + off); off += (size_t)256 * 256 * 2;     //  128 KB
    ushort* Bt1b = (ushort*)(ws + off); off += (size_t)256 * 64 * 2;      //   32 KB
    ushort* Bt2  = (ushort*)(ws + off); off += (size_t)256 * 256 * 2;     //  128 KB
    float4* pos4 = (float4*)(ws + off); off += (size_t)(NCTOT + 4) * 16;  //  256 KB
    // total ~26 MB (inside proven budget). kNN chunk partials live in
    // d_out[0:12.6MB]: dead before fused_kernel overwrites that region.
    float* out = (float*)d_out;
    int*   pidx = (int*)d_out;
    float* pdst = (float*)((char*)d_out + (size_t)NCHUNK * MTOT * 3 * 4);

    prep_kernel<<<PREP_THREADS / 256, 256, 0, stream>>>(
        x, x_skip, pos, pos_skip, W1, W2, xb, xsb, pos4, Bt1a, Bt1b, Bt2, out);
    knn_part<<<(MTOT / 1024) * NCHUNK, 256, 0, stream>>>(pos4, pos_skip, pidx, pdst);
    mid_kernel<<<NCTOT / 64 + MTOT / 256, 256, 0, stream>>>(
        xb, Bt1a, Gb, pidx, pdst, idxw, wgt);
    fused_kernel<<<MTOT / 64, 256, 0, stream>>>(xsb, Bt1b, Gb, idxw, wgt, b1, Bt2, b2, out);
}